// Round 9
// baseline (214.570 us; speedup 1.0000x reference)
//
#include <hip/hip_runtime.h>

typedef __bf16 bf16;
typedef __bf16 bf16x4 __attribute__((ext_vector_type(4)));
typedef __bf16 bf16x8 __attribute__((ext_vector_type(8)));
typedef short  s16x4  __attribute__((ext_vector_type(4)));
typedef float  f32x4  __attribute__((ext_vector_type(4)));

#define VOC 65

// workspace layout (element offsets, bf16)
#define WS_WQ 0
#define WS_WK 16384
#define WS_WV 32768
#define WS_WO 49152
#define WS_W1 65536
#define WS_W2 196608
#define WS_WF 327680   // padded [80][32]

// ---------------- prep kernels: f32 -> bf16 transpose to [col][k] (k contiguous) ----------------
__global__ void transpose_f32bf16_k(const float* __restrict__ src, bf16* __restrict__ dst,
                                    int batch, int R, int C) {
  int i = blockIdx.x * blockDim.x + threadIdx.x;
  int total = batch * R * C;
  if (i >= total) return;
  int b = i / (R * C);
  int rc = i - b * (R * C);
  int r = rc / C;
  int c = rc - r * C;
  dst[(b * C + c) * R + r] = (bf16)src[i];   // [b][R][C] -> [b][C][R]
}

__global__ void prep_wf_k(const float* __restrict__ wf, bf16* __restrict__ dst) {
  int i = blockIdx.x * blockDim.x + threadIdx.x;  // 80*32
  if (i >= 80 * 32) return;
  int c = i >> 5, r = i & 31;
  dst[i] = (c < VOC) ? (bf16)wf[r * VOC + c] : (bf16)0.0f;  // [80 cols][32 k], cols 65..79 zero
}

// ---------------- fused transformer: all-register MFMA chaining ----------------
// 16x16x16 trick: swapped-GEMM D-frag [out=4hi+r][tok=lo] IS the next MFMA16's
// A/B-frag [row=lo][k=4hi+j]. Chain QKV->scores->softmax->PV->outproj->FFN with
// ZERO LDS except a per-LN wave-private h transpose bounce (4 barriers total).

#define MFMA32(a,b,c) __builtin_amdgcn_mfma_f32_16x16x32_bf16((a),(b),(c),0,0,0)

static __device__ __forceinline__ f32x4 MFMA16(bf16x4 a, bf16x4 b, f32x4 c) {
  return __builtin_amdgcn_mfma_f32_16x16x16bf16_1k(
      __builtin_bit_cast(s16x4, a), __builtin_bit_cast(s16x4, b), c, 0, 0, 0);
}

__global__ __launch_bounds__(256)
void xformer_k(const int* __restrict__ x, const float* __restrict__ emb, const float* __restrict__ pos,
               const float* __restrict__ bq, const float* __restrict__ bk, const float* __restrict__ bv,
               const float* __restrict__ bo, const float* __restrict__ ga, const float* __restrict__ ba,
               const float* __restrict__ b1, const float* __restrict__ b2,
               const float* __restrict__ gm, const float* __restrict__ bm,
               const float* __restrict__ bfin,
               const bf16* __restrict__ ws, float* __restrict__ out)
{
  __shared__ bf16 hbounce[4][2][16][40];   // wave-private LN transpose bounce (10.2 KB)
  const int tid  = threadIdx.x;
  const int wv   = tid >> 6;
  const int lane = tid & 63;
  const int lo   = lane & 15;
  const int hi   = lane >> 4;              // 0..3
  const int seq0 = blockIdx.x * 8 + wv * 2;

  const bf16* wqT = ws + WS_WQ;            // [l*4+h][64 out][32 k]
  const bf16* wkT = ws + WS_WK;
  const bf16* wvT = ws + WS_WV;
  const bf16* woT = ws + WS_WO;            // [l][32 out][256 k]
  const bf16* w1T = ws + WS_W1;            // [l][2048 hid][32 k]
  const bf16* w2T = ws + WS_W2;            // [l][32 out][2048 k]
  const bf16* wfT = ws + WS_WF;            // [80 voc][32 k]

  const f32x4 fz = {0.f, 0.f, 0.f, 0.f};

  // Register state per seq:
  //  bh : h as MFMA32 A/B-frag  [tok=lo][dim=hi*8+j]          (bf16x8)
  //  hD0: h[tok=4hi+r][dim=lo], hD1: [dim=16+lo]              (bf16x4 each)
  bf16x8 bh[2];
  bf16x4 hD0[2], hD1[2];

  // ---- embedding: h = (emb[x] + pos) * sqrt(32), straight to registers ----
  #pragma unroll
  for (int si = 0; si < 2; ++si) {
    const int s = seq0 + si;
    int idl = x[s*16 + lo];
    idl = idl < 0 ? 0 : (idl >= VOC ? VOC - 1 : idl);
    f32x4 e0 = *(const f32x4*)(emb + idl*32 + hi*8);
    f32x4 e1 = *(const f32x4*)(emb + idl*32 + hi*8 + 4);
    f32x4 p0 = *(const f32x4*)(pos + lo*32 + hi*8);
    f32x4 p1 = *(const f32x4*)(pos + lo*32 + hi*8 + 4);
    bf16x8 hv;
    #pragma unroll
    for (int j = 0; j < 4; ++j) {
      hv[j]   = (bf16)((e0[j] + p0[j]) * 5.656854249492381f);
      hv[4+j] = (bf16)((e1[j] + p1[j]) * 5.656854249492381f);
    }
    bh[si] = hv;
    bf16x4 d0, d1;
    #pragma unroll
    for (int r = 0; r < 4; ++r) {
      int tr = hi*4 + r;
      int idr = x[s*16 + tr];
      idr = idr < 0 ? 0 : (idr >= VOC ? VOC - 1 : idr);
      d0[r] = (bf16)((emb[idr*32 + lo]      + pos[tr*32 + lo])      * 5.656854249492381f);
      d1[r] = (bf16)((emb[idr*32 + 16 + lo] + pos[tr*32 + 16 + lo]) * 5.656854249492381f);
    }
    hD0[si] = d0; hD1[si] = d1;
  }

  #pragma unroll
  for (int l = 0; l < 2; ++l) {
    // ================= attention (all-register) =================
    f32x4 accO[2][2] = {{fz,fz},{fz,fz}};  // D: [tok=4hi+r][out=n2*16+lo]
    #pragma unroll
    for (int hh = 0; hh < 4; ++hh) {
      const int hb = (l*4 + hh) * 64;
      // ---- Q,K projections (swapped MFMA32) -> MFMA16 frags ----
      bf16x4 qz[2][4], kz[2][4];
      #pragma unroll
      for (int nt = 0; nt < 4; ++nt) {
        const int wofs = (hb + nt*16 + lo)*32 + hi*8;
        bf16x8 wq8 = *(const bf16x8*)(wqT + wofs);
        bf16x8 wk8 = *(const bf16x8*)(wkT + wofs);
        f32x4 bq4 = *(const f32x4*)(bq + hb + nt*16 + hi*4);
        f32x4 bk4 = *(const f32x4*)(bk + hb + nt*16 + hi*4);
        #pragma unroll
        for (int si = 0; si < 2; ++si) {
          f32x4 dq = MFMA32(wq8, bh[si], fz);   // Q[out=nt16+4hi+r][tok=lo]
          f32x4 dk = MFMA32(wk8, bh[si], fz);
          bf16x4 pq, pk;
          #pragma unroll
          for (int r = 0; r < 4; ++r) {
            pq[r] = (bf16)(dq[r] + bq4[r]);
            pk[r] = (bf16)(dk[r] + bk4[r]);
          }
          qz[si][nt] = pq;                      // B-frag: [col=tok=lo][k=out 4hi+j]
          kz[si][nt] = pk;                      // A-frag: [row=tok=lo][k=out 4hi+j]
        }
      }
      // ---- scores + softmax (in-register) ----
      bf16x4 pp[2];
      #pragma unroll
      for (int si = 0; si < 2; ++si) {
        f32x4 sf = fz;
        #pragma unroll
        for (int nt = 0; nt < 4; ++nt) sf = MFMA16(kz[si][nt], qz[si][nt], sf);
        // D: S[key=4hi+r][query=lo]
        float e[4], mx = -3.0e4f, sm = 0.f;
        #pragma unroll
        for (int r = 0; r < 4; ++r) {
          int key = hi*4 + r;
          e[r] = (key <= lo) ? sf[r] * 0.125f : -3.0e4f;
          mx = fmaxf(mx, e[r]);
        }
        mx = fmaxf(mx, __shfl_xor(mx, 16));
        mx = fmaxf(mx, __shfl_xor(mx, 32));
        #pragma unroll
        for (int r = 0; r < 4; ++r) { e[r] = __expf(e[r] - mx); sm += e[r]; }
        sm += __shfl_xor(sm, 16);
        sm += __shfl_xor(sm, 32);
        float inv = 1.0f / sm;
        bf16x4 p4;
        #pragma unroll
        for (int r = 0; r < 4; ++r) p4[r] = (bf16)(e[r] * inv);
        pp[si] = p4;                            // B-frag: [col=query=lo][k=key 4hi+j]
      }
      // ---- V projection (original orientation) + PV + out-proj ----
      #pragma unroll
      for (int nt = 0; nt < 4; ++nt) {
        bf16x8 wv8 = *(const bf16x8*)(wvT + (hb + nt*16 + lo)*32 + hi*8);
        float bvv = bv[hb + nt*16 + lo];
        bf16x4 wo4[2];
        #pragma unroll
        for (int n2 = 0; n2 < 2; ++n2)
          wo4[n2] = *(const bf16x4*)(woT + (l*32 + n2*16 + lo)*256 + hh*64 + nt*16 + hi*4);
        #pragma unroll
        for (int si = 0; si < 2; ++si) {
          f32x4 dv = MFMA32(bh[si], wv8, fz);   // V[tok=4hi+r][vdim=nt16+lo]
          bf16x4 vz;
          #pragma unroll
          for (int r = 0; r < 4; ++r) vz[r] = (bf16)(dv[r] + bvv);
          // PV: A=vz [row=vdim-local=lo][k=key 4hi+j], B=pp -> O[vdim=nt16+4hi+r][tok=lo]
          f32x4 o = MFMA16(vz, pp[si], fz);
          bf16x4 oz;
          #pragma unroll
          for (int r = 0; r < 4; ++r) oz[r] = (bf16)o[r];
          // out-proj: A=oz [row=tok=lo][k=vdim 4hi+j], B=Wo -> D[tok=4hi+r][out=n2*16+lo]
          #pragma unroll
          for (int n2 = 0; n2 < 2; ++n2)
            accO[si][n2] = MFMA16(oz, wo4[n2], accO[si][n2]);
        }
      }
    }
    // ---- + bo + residual + LN(ga,ba); rebuild bh via wave-private bounce ----
    {
      float o0 = bo[l*32 + lo],      o1 = bo[l*32 + 16 + lo];
      float g0 = ga[l*32 + lo],      g1 = ga[l*32 + 16 + lo];
      float a0 = ba[l*32 + lo],      a1 = ba[l*32 + 16 + lo];
      #pragma unroll
      for (int si = 0; si < 2; ++si) {
        bf16x4 nh0, nh1;
        #pragma unroll
        for (int r = 0; r < 4; ++r) {
          float v0 = accO[si][0][r] + o0 + (float)hD0[si][r];
          float v1 = accO[si][1][r] + o1 + (float)hD1[si][r];
          float s1 = v0 + v1, s2 = v0*v0 + v1*v1;
          s1 += __shfl_xor(s1, 1); s2 += __shfl_xor(s2, 1);
          s1 += __shfl_xor(s1, 2); s2 += __shfl_xor(s2, 2);
          s1 += __shfl_xor(s1, 4); s2 += __shfl_xor(s2, 4);
          s1 += __shfl_xor(s1, 8); s2 += __shfl_xor(s2, 8);
          float mean = s1 * (1.f/32.f);
          float var  = s2 * (1.f/32.f) - mean*mean;
          float rs   = rsqrtf(fabsf(var) + 1e-5f);
          float h0 = (v0 - mean)*rs*g0 + a0;
          float h1 = (v1 - mean)*rs*g1 + a1;
          nh0[r] = (bf16)h0; nh1[r] = (bf16)h1;
          hbounce[wv][si][hi*4 + r][lo]      = (bf16)h0;
          hbounce[wv][si][hi*4 + r][16 + lo] = (bf16)h1;
        }
        hD0[si] = nh0; hD1[si] = nh1;
      }
      __syncthreads();
      #pragma unroll
      for (int si = 0; si < 2; ++si)
        bh[si] = *(const bf16x8*)(&hbounce[wv][si][lo][hi*8]);
    }
    // ================= FFN (all-register, no barriers) =================
    f32x4 acc2[2][2] = {{fz,fz},{fz,fz}};  // D: [tok=4hi+r][out=n2*16+lo]
    const bf16* w1l = w1T + l*65536;
    const bf16* w2l = w2T + l*65536;
    const float* b1l = b1 + l*2048;
    for (int kk = 0; kk < 64; ++kk) {
      #pragma unroll
      for (int c = 0; c < 2; ++c) {
        const int hidb = kk*32 + c*16;
        bf16x8 w1f = *(const bf16x8*)(w1l + (hidb + lo)*32 + hi*8);
        f32x4 b14 = *(const f32x4*)(b1l + hidb + hi*4);
        bf16x4 w2b[2];
        #pragma unroll
        for (int n2 = 0; n2 < 2; ++n2)
          w2b[n2] = *(const bf16x4*)(w2l + (n2*16 + lo)*2048 + hidb + hi*4);
        #pragma unroll
        for (int si = 0; si < 2; ++si) {
          f32x4 dm = MFMA32(w1f, bh[si], fz);   // m[hid=hidb+4hi+r][tok=lo]
          bf16x4 mz;
          #pragma unroll
          for (int r = 0; r < 4; ++r) mz[r] = (bf16)fmaxf(dm[r] + b14[r], 0.f);
          // GEMM2: A=mz [row=tok=lo][k=hid 4hi+j], B=W2 -> D[tok=4hi+r][out=n2*16+lo]
          #pragma unroll
          for (int n2 = 0; n2 < 2; ++n2)
            acc2[si][n2] = MFMA16(mz, w2b[n2], acc2[si][n2]);
        }
      }
    }
    // ---- + b2 + residual + LN(gm,bm); rebuild bh ----
    {
      float c0 = b2[l*32 + lo],      c1 = b2[l*32 + 16 + lo];
      float g0 = gm[l*32 + lo],      g1 = gm[l*32 + 16 + lo];
      float a0 = bm[l*32 + lo],      a1 = bm[l*32 + 16 + lo];
      #pragma unroll
      for (int si = 0; si < 2; ++si) {
        bf16x4 nh0, nh1;
        #pragma unroll
        for (int r = 0; r < 4; ++r) {
          float v0 = acc2[si][0][r] + c0 + (float)hD0[si][r];
          float v1 = acc2[si][1][r] + c1 + (float)hD1[si][r];
          float s1 = v0 + v1, s2 = v0*v0 + v1*v1;
          s1 += __shfl_xor(s1, 1); s2 += __shfl_xor(s2, 1);
          s1 += __shfl_xor(s1, 2); s2 += __shfl_xor(s2, 2);
          s1 += __shfl_xor(s1, 4); s2 += __shfl_xor(s2, 4);
          s1 += __shfl_xor(s1, 8); s2 += __shfl_xor(s2, 8);
          float mean = s1 * (1.f/32.f);
          float var  = s2 * (1.f/32.f) - mean*mean;
          float rs   = rsqrtf(fabsf(var) + 1e-5f);
          float h0 = (v0 - mean)*rs*g0 + a0;
          float h1 = (v1 - mean)*rs*g1 + a1;
          nh0[r] = (bf16)h0; nh1[r] = (bf16)h1;
          hbounce[wv][si][hi*4 + r][lo]      = (bf16)h0;
          hbounce[wv][si][hi*4 + r][16 + lo] = (bf16)h1;
        }
        hD0[si] = nh0; hD1[si] = nh1;
      }
      __syncthreads();
      #pragma unroll
      for (int si = 0; si < 2; ++si)
        bh[si] = *(const bf16x8*)(&hbounce[wv][si][lo][hi*8]);
    }
  }

  // ---- final classifier: h @ Wf + bf -> out [s,16,65] (f32) ----
  #pragma unroll
  for (int si = 0; si < 2; ++si) {
    const int s = seq0 + si;
    bf16x8 a = bh[si];
    #pragma unroll
    for (int nt = 0; nt < 5; ++nt) {
      bf16x8 w = *(const bf16x8*)(wfT + (nt*16 + lo)*32 + hi*8);
      f32x4 d = MFMA32(a, w, fz);              // D[tok=4hi+r][voc=nt16+lo]
      int col = nt*16 + lo;
      if (col < VOC) {
        float bb = bfin[col];
        #pragma unroll
        for (int r = 0; r < 4; ++r)
          out[(s*16 + hi*4 + r)*VOC + col] = d[r] + bb;
      }
    }
  }
}

extern "C" void kernel_launch(void* const* d_in, const int* in_sizes, int n_in,
                              void* d_out, int out_size, void* d_ws, size_t ws_size,
                              hipStream_t stream) {
  const int*   x   = (const int*)d_in[0];
  const float* emb = (const float*)d_in[1];
  const float* pos = (const float*)d_in[2];
  const float* Wq  = (const float*)d_in[3];
  const float* bq  = (const float*)d_in[4];
  const float* Wk  = (const float*)d_in[5];
  const float* bk  = (const float*)d_in[6];
  const float* Wv  = (const float*)d_in[7];
  const float* bv  = (const float*)d_in[8];
  const float* Wo  = (const float*)d_in[9];
  const float* bo  = (const float*)d_in[10];
  const float* ga  = (const float*)d_in[11];
  const float* ba  = (const float*)d_in[12];
  const float* W1  = (const float*)d_in[13];
  const float* b1  = (const float*)d_in[14];
  const float* W2  = (const float*)d_in[15];
  const float* b2  = (const float*)d_in[16];
  const float* gm  = (const float*)d_in[17];
  const float* bm  = (const float*)d_in[18];
  const float* Wf  = (const float*)d_in[19];
  const float* bfin= (const float*)d_in[20];

  bf16* ws = (bf16*)d_ws;

  // transpose weights (f32 -> bf16) into MFMA [out][k] layout (k contiguous)
  transpose_f32bf16_k<<<64, 256, 0, stream>>>(Wq, ws + WS_WQ, 8, 32, 64);
  transpose_f32bf16_k<<<64, 256, 0, stream>>>(Wk, ws + WS_WK, 8, 32, 64);
  transpose_f32bf16_k<<<64, 256, 0, stream>>>(Wv, ws + WS_WV, 8, 32, 64);
  transpose_f32bf16_k<<<64, 256, 0, stream>>>(Wo, ws + WS_WO, 2, 256, 32);
  transpose_f32bf16_k<<<512, 256, 0, stream>>>(W1, ws + WS_W1, 2, 32, 2048);
  transpose_f32bf16_k<<<512, 256, 0, stream>>>(W2, ws + WS_W2, 2, 2048, 32);
  prep_wf_k<<<10, 256, 0, stream>>>(Wf, ws + WS_WF);

  // fused transformer: 512 blocks x 256 threads (4 waves x 2 seqs), 4 barriers total
  xformer_k<<<512, 256, 0, stream>>>(x, emb, pos, bq, bk, bv, bo, ga, ba,
                                     b1, b2, gm, bm, bfin,
                                     ws, (float*)d_out);
}